// Round 7
// baseline (316.606 us; speedup 1.0000x reference)
//
#include <hip/hip_runtime.h>
#include <hip/hip_bf16.h>
#include <math.h>

// Problem constants (fixed by setup_inputs)
constexpr int B = 4;
constexpr int L = 2048;
constexpr int H = 8;
constexpr int D = 64;
constexpr int S = 40;   // sample_k
constexpr int U = 40;   // top-u queries
constexpr int C = 32;   // cumsum chunks
constexpr int CHUNK = L / C;   // 64
constexpr int NSEG = 16;       // key segments for attention
constexpr int SEG  = L / NSEG; // 128
constexpr int PAH  = 688;      // per-h LDS stride

// ---------------------------------------------------------------------------
// L1 fat kernel: blocks [0,256) = cumsum_part; blocks [256, 256+B*L) = compute_M.
// (unchanged from round 6; its 1.31M "conflicts" are 1 cycle/half-wave store —
// benign; kernel sits at ~15.4 TB/s effective L2 gather.)
// ---------------------------------------------------------------------------
__global__ void fused_Mpart(const float* __restrict__ q,
                            const float* __restrict__ k,
                            const float* __restrict__ v,
                            const int*   __restrict__ samp,
                            float* __restrict__ M,
                            float* __restrict__ part) {
    __shared__ float pa[H * PAH];
    int tid = threadIdx.x;

    if (blockIdx.x < 256) {
        // ---- cumsum_part ----
        int idx = blockIdx.x * 256 + tid;   // [0, B*C*H*D) = 65536
        int b   = idx >> 14;
        int rem = idx & 16383;
        int c   = rem >> 9;
        int hd  = rem & 511;
        const float* base = v + ((size_t)(b * L + c * CHUNK) * H * D) + hd;
        float s = 0.f;
        for (int i = 0; i < CHUNK; i++) s += base[(size_t)i * (H * D)];
        int h = hd >> 6, d = hd & 63;
        part[((size_t)(b * H + h) * C + c) * D + d] = s;
        return;
    }

    // ---- compute_M ----
    int blk = blockIdx.x - 256;        // [0, B*L)
    int xcd = blk & 7;
    int b   = xcd >> 1;
    int l   = ((blk >> 3) << 1) | (xcd & 1);
    int h      = tid >> 5;             // 0..7
    int lane32 = tid & 31;
    int g  = lane32 >> 4;              // sample sub-slot (0..1)
    int d4 = lane32 & 15;              // float4 index within row

    const float4 qv = *(const float4*)(q + ((size_t)(b * L + l) * H + h) * D + d4 * 4);
    const int* srow = samp + l * S;
    float* pah = pa + h * PAH;

#pragma unroll 10
    for (int sb = 0; sb < S; sb += 2) {
        int i0 = srow[sb];
        int i1 = srow[sb + 1];
        int idx = g ? i1 : i0;
        int s = sb + g;
        float4 kv = *(const float4*)(k + ((size_t)(b * L + idx) * H + h) * D + d4 * 4);
        pah[s * 17 + d4] = qv.x * kv.x + qv.y * kv.y + qv.z * kv.z + qv.w * kv.w;
    }
    __syncthreads();

    int s1 = lane32;
    float t0 = 0.f, t1 = 0.f, t2 = 0.f, t3 = 0.f;
#pragma unroll
    for (int i = 0; i < 16; i += 4) {
        t0 += pah[s1 * 17 + i];
        t1 += pah[s1 * 17 + i + 1];
        t2 += pah[s1 * 17 + i + 2];
        t3 += pah[s1 * 17 + i + 3];
    }
    float dot1 = (t0 + t1) + (t2 + t3);
    float mv = dot1, sv = dot1;
    if (lane32 < S - 32) {
        int s2 = 32 + lane32;
        float u0 = 0.f, u1 = 0.f, u2 = 0.f, u3 = 0.f;
#pragma unroll
        for (int i = 0; i < 16; i += 4) {
            u0 += pah[s2 * 17 + i];
            u1 += pah[s2 * 17 + i + 1];
            u2 += pah[s2 * 17 + i + 2];
            u3 += pah[s2 * 17 + i + 3];
        }
        float dot2 = (u0 + u1) + (u2 + u3);
        mv = fmaxf(mv, dot2);
        sv += dot2;
    }
#pragma unroll
    for (int off = 1; off <= 16; off <<= 1) {
        mv = fmaxf(mv, __shfl_xor(mv, off));
        sv += __shfl_xor(sv, off);
    }
    if (lane32 == 0) M[(size_t)(b * H + h) * L + l] = mv - sv * (1.0f / (float)L);
}

// ---------------------------------------------------------------------------
// L2 fat kernel, 256 threads/block.
// blocks [0,32): topk — ONE WAVE per (b,h) (tid<64), top-2 per u64 butterfly
//   round, no barriers. (key = sortable<<32 | ~idx: tie -> lowest index)
// blocks [32, 32+256): cumsum_write, 256 thr (4 waves/block for latency hide).
// ---------------------------------------------------------------------------
__global__ void fused_topk_cumsum(const float* __restrict__ M,
                                  const float* __restrict__ v,
                                  const float* __restrict__ part,
                                  int* __restrict__ Mtop,
                                  float* __restrict__ out) {
    int tid = threadIdx.x;

    if (blockIdx.x >= 32) {
        // ---- cumsum_write ----
        int idx = (blockIdx.x - 32) * 256 + tid;  // [0, 65536)
        int b   = idx >> 14;
        int rem = idx & 16383;
        int c   = rem >> 9;                        // block-uniform
        int hd  = rem & 511;
        int h = hd >> 6, d = hd & 63;

        float run = 0.f;
        for (int cc = 0; cc < c; cc++)
            run += part[((size_t)(b * H + h) * C + cc) * D + d];

        const float* base  = v   + ((size_t)(b * L + c * CHUNK) * H * D) + hd;
        float*       obase = out + ((size_t)(b * L + c * CHUNK) * H * D) + hd;
        for (int i = 0; i < CHUNK; i++) {
            run += base[(size_t)i * (H * D)];
            obase[(size_t)i * (H * D)] = run;
        }
        return;
    }

    // ---- topk (single wave; threads >= 64 exit; no barriers used) ----
    if (tid >= 64) return;
    int bh   = blockIdx.x;
    int base = tid * 32;
    const float* row = M + (size_t)bh * L;

    unsigned int vals[32];
#pragma unroll
    for (int r4 = 0; r4 < 8; r4++) {
        float4 f = *(const float4*)(row + base + r4 * 4);
        const float ff[4] = {f.x, f.y, f.z, f.w};
#pragma unroll
        for (int j = 0; j < 4; j++) {
            unsigned int i = __float_as_uint(ff[j]);
            vals[r4 * 4 + j] = (i & 0x80000000u) ? ~i : (i | 0x80000000u);
        }
    }

    unsigned long long k1 = 0ull, k2 = 0ull;
#pragma unroll
    for (int r = 0; r < 32; r++) {
        unsigned long long kk =
            ((unsigned long long)vals[r] << 32) | (unsigned int)~(base + r);
        if (kk > k1) { k2 = k1; k1 = kk; }
        else if (kk > k2) { k2 = kk; }
    }

    for (int it = 0; it < U; it += 2) {
        unsigned long long a1 = k1, a2 = k2;
#pragma unroll
        for (int off = 1; off < 64; off <<= 1) {
            unsigned long long o1 = __shfl_xor(a1, off);
            unsigned long long o2 = __shfl_xor(a2, off);
            unsigned long long hi = a1 > o1 ? a1 : o1;
            unsigned long long lo = a1 > o1 ? o1 : a1;
            unsigned long long ss = a2 > o2 ? a2 : o2;
            a1 = hi;
            a2 = lo > ss ? lo : ss;
        }
        int i1 = (int)~(unsigned int)a1;
        int i2 = (int)~(unsigned int)a2;
        if (tid == 0) {
            Mtop[bh * U + it]     = i1;
            Mtop[bh * U + it + 1] = i2;
        }
        bool own1 = (i1 >> 5) == tid;
        bool own2 = (i2 >> 5) == tid;
        if (own1 | own2) {
            int r1 = own1 ? (i1 & 31) : 32;
            int r2 = own2 ? (i2 & 31) : 32;
#pragma unroll
            for (int r = 0; r < 32; r++)
                if (r == r1 || r == r2) vals[r] = 0u;
            k1 = 0ull; k2 = 0ull;
#pragma unroll
            for (int r = 0; r < 32; r++) {
                unsigned long long kk =
                    ((unsigned long long)vals[r] << 32) | (unsigned int)~(base + r);
                if (kk > k1) { k2 = k1; k1 = kk; }
                else if (kk > k2) { k2 = kk; }
            }
        }
    }
}

// ---------------------------------------------------------------------------
// K5a: batched-query segment attention, v2.
// Softmax folded into the score-GEMM epilogue: for row u, its ug's 32 jg-lanes
// hold ALL 128 scores -> 5-shfl max + 5-shfl sum per u, Sc written already
// exponentiated, ml written from lane jg==0. PV retiled 5u x 4d x half-j with
// b128 V reads; halves combined through the retired Qs buffer.
// ---------------------------------------------------------------------------
__global__ __launch_bounds__(256, 2)
void attn_batched(const float* __restrict__ q,
                  const float* __restrict__ k,
                  const float* __restrict__ v,
                  const int*   __restrict__ Mtop,
                  float* __restrict__ ml,
                  float* __restrict__ pacc) {
    int blk = blockIdx.x;              // [0, B*H*NSEG) = 512
    int xcd = blk & 7;
    int b   = xcd >> 1;
    int r   = ((blk >> 3) << 1) | (xcd & 1);   // [0, H*NSEG)
    int h   = r >> 4;
    int seg = r & 15;
    int bh  = b * H + h;
    int j0  = seg * SEG;
    int tid = threadIdx.x;

    __shared__ float Qs[U * D];        // 10.2 KB (Q; reused as PV half-buffer)
    __shared__ float KV[SEG * D];      // 32.8 KB (K tile, then V tile)
    __shared__ float Sc[U * SEG];      // 20.5 KB (exp-ed scores, swizzled)
    __shared__ int   qis[U];

    if (tid < U) qis[tid] = Mtop[bh * U + tid];
    __syncthreads();

    for (int i = tid; i < U * 16; i += 256) {
        int u = i >> 4, d4 = i & 15;
        *(float4*)&Qs[u * D + d4 * 4] =
            *(const float4*)(q + ((size_t)(b * L + qis[u]) * H + h) * D + d4 * 4);
    }
    for (int i = tid; i < SEG * 16; i += 256) {
        int rr = i >> 4, d4 = i & 15;
        float4 kv = *(const float4*)(k + ((size_t)(b * L + j0 + rr) * H + h) * D + d4 * 4);
        *(float4*)&KV[rr * D + (d4 ^ (rr & 15)) * 4] = kv;
    }
    __syncthreads();

    // ---- score GEMM: thread tile 5u x 4j ----
    int ug = tid >> 5;        // 0..7
    int jg = tid & 31;        // 0..31
    int jlow = jg & 15;
    float acc[5][4];
#pragma unroll
    for (int uu = 0; uu < 5; uu++)
#pragma unroll
        for (int jj = 0; jj < 4; jj++) acc[uu][jj] = 0.f;

#pragma unroll
    for (int kk4 = 0; kk4 < 16; kk4++) {
        float4 kf[4];
        int slot = kk4 ^ jlow;
#pragma unroll
        for (int jj = 0; jj < 4; jj++)
            kf[jj] = *(const float4*)&KV[(jg + 32 * jj) * D + slot * 4];
#pragma unroll
        for (int uu = 0; uu < 5; uu++) {
            float4 qf = *(const float4*)&Qs[(ug * 5 + uu) * D + kk4 * 4];
#pragma unroll
            for (int jj = 0; jj < 4; jj++) {
                acc[uu][jj] += qf.x * kf[jj].x + qf.y * kf[jj].y
                             + qf.z * kf[jj].z + qf.w * kf[jj].w;
            }
        }
    }

    // ---- softmax epilogue (per u: wave-group reductions, no LDS phase) ----
#pragma unroll
    for (int uu = 0; uu < 5; uu++) {
        int u  = ug * 5 + uu;
        int um = u & 15;
        int nk = qis[u] + 1 - j0;
        nk = nk < 0 ? 0 : (nk > SEG ? SEG : nk);
        float sc4[4];
        float mv = -INFINITY;
#pragma unroll
        for (int jj = 0; jj < 4; jj++) {
            int j = jg + 32 * jj;
            sc4[jj] = acc[uu][jj] * 0.125f;     // 1/sqrt(64)
            if (j < nk) mv = fmaxf(mv, sc4[jj]);
        }
#pragma unroll
        for (int off = 1; off <= 16; off <<= 1)
            mv = fmaxf(mv, __shfl_xor(mv, off));
        float ls = 0.f;
#pragma unroll
        for (int jj = 0; jj < 4; jj++) {
            int j = jg + 32 * jj;
            float e = (j < nk) ? __expf(sc4[jj] - mv) : 0.f;
            Sc[u * SEG + 4 * ((j >> 2) ^ um) + (j & 3)] = e;
            ls += e;
        }
#pragma unroll
        for (int off = 1; off <= 16; off <<= 1)
            ls += __shfl_xor(ls, off);
        if (jg == 0) {
            size_t mli = 2 * ((size_t)(bh * U + u) * NSEG + seg);
            ml[mli]     = mv;                   // -inf if fully masked
            ml[mli + 1] = ls;
        }
    }
    __syncthreads();   // (A): Sc visible; all K/Q reads done

    // stage V tile into KV
    for (int i = tid; i < SEG * 16; i += 256) {
        int rr = i >> 4, d4 = i & 15;
        float4 vv = *(const float4*)(v + ((size_t)(b * L + j0 + rr) * H + h) * D + d4 * 4);
        *(float4*)&KV[rr * D + (d4 ^ (rr & 15)) * 4] = vv;
    }
    __syncthreads();   // (B)

    // ---- PV GEMM: thread tile 5u x 4d over half the j range ----
    int r5 = tid & 31;
    int dg = r5 >> 1;          // float4 slot in d (0..15)
    int jh = r5 & 1;           // j-half
    float4 a4[5];
#pragma unroll
    for (int uu = 0; uu < 5; uu++) a4[uu] = make_float4(0.f, 0.f, 0.f, 0.f);

#pragma unroll 4
    for (int jq = 0; jq < 16; jq++) {
        int j4 = jh * 16 + jq;
        float4 pf[5];
#pragma unroll
        for (int uu = 0; uu < 5; uu++) {
            int u = ug * 5 + uu;
            pf[uu] = *(const float4*)&Sc[u * SEG + 4 * (j4 ^ (u & 15))];
        }
#pragma unroll
        for (int jj = 0; jj < 4; jj++) {
            int j = j4 * 4 + jj;
            float4 vv = *(const float4*)&KV[j * D + (dg ^ (j & 15)) * 4];
#pragma unroll
            for (int uu = 0; uu < 5; uu++) {
                float p = ((const float*)&pf[uu])[jj];
                a4[uu].x += p * vv.x;
                a4[uu].y += p * vv.y;
                a4[uu].z += p * vv.z;
                a4[uu].w += p * vv.w;
            }
        }
    }
    // combine j-halves via retired Qs buffer
    if (jh == 1) {
#pragma unroll
        for (int uu = 0; uu < 5; uu++)
            *(float4*)&Qs[(ug * 5 + uu) * D + dg * 4] = a4[uu];
    }
    __syncthreads();   // (C)
    if (jh == 0) {
#pragma unroll
        for (int uu = 0; uu < 5; uu++) {
            int u = ug * 5 + uu;
            float4 o = *(const float4*)&Qs[u * D + dg * 4];
            o.x += a4[uu].x; o.y += a4[uu].y; o.z += a4[uu].z; o.w += a4[uu].w;
            *(float4*)&pacc[((size_t)(bh * U + u) * NSEG + seg) * D + dg * 4] = o;
        }
    }
}

// ---------------------------------------------------------------------------
// K5b: combine NSEG partials per (b,h,u), write the output row.
// ---------------------------------------------------------------------------
__global__ void attn_combine(const int* __restrict__ Mtop,
                             const float* __restrict__ ml,
                             const float* __restrict__ pacc,
                             float* __restrict__ out) {
    int blk = blockIdx.x;          // bh*U + u
    int u  = blk % U;
    int bh = blk / U;
    int h  = bh % H;
    int b  = bh / H;
    int d  = threadIdx.x;
    int qi = Mtop[bh * U + u];

    size_t r0 = (size_t)blk * NSEG;
    float m = -INFINITY;
#pragma unroll
    for (int s = 0; s < NSEG; s++) m = fmaxf(m, ml[2 * (r0 + s)]);

    float lt = 0.f, acc = 0.f;
#pragma unroll
    for (int s = 0; s < NSEG; s++) {
        float ms = ml[2 * (r0 + s)];
        float w  = __expf(ms - m);
        lt  += ml[2 * (r0 + s) + 1] * w;
        acc += pacc[(r0 + s) * D + d] * w;
    }
    out[((size_t)(b * L + qi) * H + h) * D + d] = acc / lt;
}

// ---------------------------------------------------------------------------
extern "C" void kernel_launch(void* const* d_in, const int* in_sizes, int n_in,
                              void* d_out, int out_size, void* d_ws, size_t ws_size,
                              hipStream_t stream) {
    const float* q    = (const float*)d_in[0];
    const float* k    = (const float*)d_in[1];
    const float* v    = (const float*)d_in[2];
    const int*   samp = (const int*)d_in[3];
    float* out = (float*)d_out;

    // workspace layout
    float* M    = (float*)d_ws;                        // B*H*L
    int*   Mtop = (int*)(M + (size_t)B * H * L);       // B*H*U
    float* part = (float*)(Mtop + (size_t)B * H * U);  // B*H*C*D
    float* ml   = part + (size_t)B * H * C * D;        // B*H*U*NSEG*2
    float* pacc = ml + (size_t)B * H * U * NSEG * 2;   // B*H*U*NSEG*D

    fused_Mpart<<<256 + B * L, 256, 0, stream>>>(q, k, v, samp, M, part);
    fused_topk_cumsum<<<32 + 256, 256, 0, stream>>>(M, v, part, Mtop, out);
    attn_batched<<<B * H * NSEG, 256, 0, stream>>>(q, k, v, Mtop, ml, pacc);
    attn_combine<<<B * H * U, 64, 0, stream>>>(Mtop, ml, pacc, out);
}

// Round 8
// 184.371 us; speedup vs baseline: 1.7172x; 1.7172x over previous
//
#include <hip/hip_runtime.h>
#include <hip/hip_bf16.h>
#include <math.h>

// Problem constants (fixed by setup_inputs)
constexpr int B = 4;
constexpr int L = 2048;
constexpr int H = 8;
constexpr int D = 64;
constexpr int S = 40;   // sample_k
constexpr int U = 40;   // top-u queries
constexpr int C = 32;   // cumsum chunks
constexpr int CHUNK = L / C;   // 64
constexpr int NSEG = 16;       // key segments for attention
constexpr int SEG  = L / NSEG; // 128
constexpr int PAH  = 688;      // per-h LDS stride

// ---------------------------------------------------------------------------
// L1 fat kernel: blocks [0,256) = cumsum_part; blocks [256, 256+B*L) = compute_M.
// ---------------------------------------------------------------------------
__global__ void fused_Mpart(const float* __restrict__ q,
                            const float* __restrict__ k,
                            const float* __restrict__ v,
                            const int*   __restrict__ samp,
                            float* __restrict__ M,
                            float* __restrict__ part) {
    __shared__ float pa[H * PAH];
    int tid = threadIdx.x;

    if (blockIdx.x < 256) {
        // ---- cumsum_part ----
        int idx = blockIdx.x * 256 + tid;   // [0, B*C*H*D) = 65536
        int b   = idx >> 14;
        int rem = idx & 16383;
        int c   = rem >> 9;
        int hd  = rem & 511;
        const float* base = v + ((size_t)(b * L + c * CHUNK) * H * D) + hd;
        float s = 0.f;
        for (int i = 0; i < CHUNK; i++) s += base[(size_t)i * (H * D)];
        int h = hd >> 6, d = hd & 63;
        part[((size_t)(b * H + h) * C + c) * D + d] = s;
        return;
    }

    // ---- compute_M ----
    int blk = blockIdx.x - 256;        // [0, B*L)
    int xcd = blk & 7;
    int b   = xcd >> 1;
    int l   = ((blk >> 3) << 1) | (xcd & 1);
    int h      = tid >> 5;             // 0..7
    int lane32 = tid & 31;
    int g  = lane32 >> 4;              // sample sub-slot (0..1)
    int d4 = lane32 & 15;              // float4 index within row

    const float4 qv = *(const float4*)(q + ((size_t)(b * L + l) * H + h) * D + d4 * 4);
    const int* srow = samp + l * S;
    float* pah = pa + h * PAH;

#pragma unroll 10
    for (int sb = 0; sb < S; sb += 2) {
        int i0 = srow[sb];
        int i1 = srow[sb + 1];
        int idx = g ? i1 : i0;
        int s = sb + g;
        float4 kv = *(const float4*)(k + ((size_t)(b * L + idx) * H + h) * D + d4 * 4);
        pah[s * 17 + d4] = qv.x * kv.x + qv.y * kv.y + qv.z * kv.z + qv.w * kv.w;
    }
    __syncthreads();

    int s1 = lane32;
    float t0 = 0.f, t1 = 0.f, t2 = 0.f, t3 = 0.f;
#pragma unroll
    for (int i = 0; i < 16; i += 4) {
        t0 += pah[s1 * 17 + i];
        t1 += pah[s1 * 17 + i + 1];
        t2 += pah[s1 * 17 + i + 2];
        t3 += pah[s1 * 17 + i + 3];
    }
    float dot1 = (t0 + t1) + (t2 + t3);
    float mv = dot1, sv = dot1;
    if (lane32 < S - 32) {
        int s2 = 32 + lane32;
        float u0 = 0.f, u1 = 0.f, u2 = 0.f, u3 = 0.f;
#pragma unroll
        for (int i = 0; i < 16; i += 4) {
            u0 += pah[s2 * 17 + i];
            u1 += pah[s2 * 17 + i + 1];
            u2 += pah[s2 * 17 + i + 2];
            u3 += pah[s2 * 17 + i + 3];
        }
        float dot2 = (u0 + u1) + (u2 + u3);
        mv = fmaxf(mv, dot2);
        sv += dot2;
    }
#pragma unroll
    for (int off = 1; off <= 16; off <<= 1) {
        mv = fmaxf(mv, __shfl_xor(mv, off));
        sv += __shfl_xor(sv, off);
    }
    if (lane32 == 0) M[(size_t)(b * H + h) * L + l] = mv - sv * (1.0f / (float)L);
}

// ---------------------------------------------------------------------------
// L2 fat kernel, 64 threads/block (R6 layout).
// blocks [0,32): topk — ONE WAVE per (b,h), top-2 per u64 butterfly round.
// blocks [32, 32+1024): cumsum_write.
// ---------------------------------------------------------------------------
__global__ void fused_topk_cumsum(const float* __restrict__ M,
                                  const float* __restrict__ v,
                                  const float* __restrict__ part,
                                  int* __restrict__ Mtop,
                                  float* __restrict__ out) {
    int tid = threadIdx.x;   // 0..63

    if (blockIdx.x >= 32) {
        // ---- cumsum_write ----
        int idx = (blockIdx.x - 32) * 64 + tid;   // [0, 65536)
        int b   = idx >> 14;
        int rem = idx & 16383;
        int c   = rem >> 9;                        // block-uniform
        int hd  = rem & 511;
        int h = hd >> 6, d = hd & 63;

        float run = 0.f;
        for (int cc = 0; cc < c; cc++)
            run += part[((size_t)(b * H + h) * C + cc) * D + d];

        const float* base  = v   + ((size_t)(b * L + c * CHUNK) * H * D) + hd;
        float*       obase = out + ((size_t)(b * L + c * CHUNK) * H * D) + hd;
        for (int i = 0; i < CHUNK; i++) {
            run += base[(size_t)i * (H * D)];
            obase[(size_t)i * (H * D)] = run;
        }
        return;
    }

    // ---- topk ----
    int bh   = blockIdx.x;
    int base = tid * 32;
    const float* row = M + (size_t)bh * L;

    unsigned int vals[32];
#pragma unroll
    for (int r4 = 0; r4 < 8; r4++) {
        float4 f = *(const float4*)(row + base + r4 * 4);
        const float ff[4] = {f.x, f.y, f.z, f.w};
#pragma unroll
        for (int j = 0; j < 4; j++) {
            unsigned int i = __float_as_uint(ff[j]);
            vals[r4 * 4 + j] = (i & 0x80000000u) ? ~i : (i | 0x80000000u);
        }
    }

    unsigned long long k1 = 0ull, k2 = 0ull;
#pragma unroll
    for (int r = 0; r < 32; r++) {
        unsigned long long kk =
            ((unsigned long long)vals[r] << 32) | (unsigned int)~(base + r);
        if (kk > k1) { k2 = k1; k1 = kk; }
        else if (kk > k2) { k2 = kk; }
    }

    for (int it = 0; it < U; it += 2) {
        unsigned long long a1 = k1, a2 = k2;
#pragma unroll
        for (int off = 1; off < 64; off <<= 1) {
            unsigned long long o1 = __shfl_xor(a1, off);
            unsigned long long o2 = __shfl_xor(a2, off);
            unsigned long long hi = a1 > o1 ? a1 : o1;
            unsigned long long lo = a1 > o1 ? o1 : a1;
            unsigned long long ss = a2 > o2 ? a2 : o2;
            a1 = hi;
            a2 = lo > ss ? lo : ss;
        }
        int i1 = (int)~(unsigned int)a1;
        int i2 = (int)~(unsigned int)a2;
        if (tid == 0) {
            Mtop[bh * U + it]     = i1;
            Mtop[bh * U + it + 1] = i2;
        }
        bool own1 = (i1 >> 5) == tid;
        bool own2 = (i2 >> 5) == tid;
        if (own1 | own2) {
            int r1 = own1 ? (i1 & 31) : 32;
            int r2 = own2 ? (i2 & 31) : 32;
#pragma unroll
            for (int r = 0; r < 32; r++)
                if (r == r1 || r == r2) vals[r] = 0u;
            k1 = 0ull; k2 = 0ull;
#pragma unroll
            for (int r = 0; r < 32; r++) {
                unsigned long long kk =
                    ((unsigned long long)vals[r] << 32) | (unsigned int)~(base + r);
                if (kk > k1) { k2 = k1; k1 = kk; }
                else if (kk > k2) { k2 = kk; }
            }
        }
    }
}

// ---------------------------------------------------------------------------
// K5a: batched-query segment attention (exact R6 version — known-good ~30 µs).
// ---------------------------------------------------------------------------
__global__ __launch_bounds__(256, 2)
void attn_batched(const float* __restrict__ q,
                  const float* __restrict__ k,
                  const float* __restrict__ v,
                  const int*   __restrict__ Mtop,
                  float* __restrict__ ml,
                  float* __restrict__ pacc) {
    int blk = blockIdx.x;              // [0, B*H*NSEG) = 512
    int xcd = blk & 7;
    int b   = xcd >> 1;
    int r   = ((blk >> 3) << 1) | (xcd & 1);   // [0, H*NSEG)
    int h   = r >> 4;
    int seg = r & 15;
    int bh  = b * H + h;
    int j0  = seg * SEG;
    int tid = threadIdx.x;

    __shared__ float Qs[U * D];        // 10.2 KB
    __shared__ float KV[SEG * D];      // 32.8 KB (K tile, then reused for V)
    __shared__ float Sc[U * SEG];      // 20.5 KB (slot-swizzled by u&15)
    __shared__ float red[U * 4];
    __shared__ float mrow[U];
    __shared__ int   qis[U];

    if (tid < U) qis[tid] = Mtop[bh * U + tid];
    __syncthreads();

    for (int i = tid; i < U * 16; i += 256) {
        int u = i >> 4, d4 = i & 15;
        *(float4*)&Qs[u * D + d4 * 4] =
            *(const float4*)(q + ((size_t)(b * L + qis[u]) * H + h) * D + d4 * 4);
    }
    for (int i = tid; i < SEG * 16; i += 256) {
        int rr = i >> 4, d4 = i & 15;
        float4 kv = *(const float4*)(k + ((size_t)(b * L + j0 + rr) * H + h) * D + d4 * 4);
        *(float4*)&KV[rr * D + (d4 ^ (rr & 15)) * 4] = kv;
    }
    __syncthreads();

    // ---- score GEMM: thread tile 5u x 4j ----
    int ug = tid >> 5;        // 0..7
    int jg = tid & 31;        // 0..31
    int jlow = jg & 15;
    float acc[5][4];
#pragma unroll
    for (int uu = 0; uu < 5; uu++)
#pragma unroll
        for (int jj = 0; jj < 4; jj++) acc[uu][jj] = 0.f;

#pragma unroll
    for (int kk4 = 0; kk4 < 16; kk4++) {
        float4 kf[4];
        int slot = kk4 ^ jlow;
#pragma unroll
        for (int jj = 0; jj < 4; jj++)
            kf[jj] = *(const float4*)&KV[(jg + 32 * jj) * D + slot * 4];
#pragma unroll
        for (int uu = 0; uu < 5; uu++) {
            float4 qf = *(const float4*)&Qs[(ug * 5 + uu) * D + kk4 * 4];
#pragma unroll
            for (int jj = 0; jj < 4; jj++) {
                acc[uu][jj] += qf.x * kf[jj].x + qf.y * kf[jj].y
                             + qf.z * kf[jj].z + qf.w * kf[jj].w;
            }
        }
    }
#pragma unroll
    for (int uu = 0; uu < 5; uu++) {
        int u = ug * 5 + uu;
        int um = u & 15;
#pragma unroll
        for (int jj = 0; jj < 4; jj++) {
            int j = jg + 32 * jj;
            Sc[u * SEG + 4 * ((j >> 2) ^ um) + (j & 3)] = acc[uu][jj] * 0.125f;
        }
    }
    __syncthreads();   // (A): Sc visible; all K reads done

    // stage V tile into KV
    for (int i = tid; i < SEG * 16; i += 256) {
        int rr = i >> 4, d4 = i & 15;
        float4 vv = *(const float4*)(v + ((size_t)(b * L + j0 + rr) * H + h) * D + d4 * 4);
        *(float4*)&KV[rr * D + (d4 ^ (rr & 15)) * 4] = vv;
    }

    // ---- masked softmax partials ----
    int su = tid >> 2, sq = tid & 3;
    int nkc = 0;
    if (tid < U * 4) {
        int nk = qis[su] + 1 - j0;
        nkc = nk < 0 ? 0 : (nk > SEG ? SEG : nk);
        int um = su & 15;
        float mvx = -INFINITY;
        for (int t = 0; t < 32; t++) {
            int i = sq + 4 * t;
            if (i < nkc) mvx = fmaxf(mvx, Sc[su * SEG + 4 * ((i >> 2) ^ um) + (i & 3)]);
        }
        red[su * 4 + sq] = mvx;
    }
    __syncthreads();   // (B): also covers V staging
    if (tid < U) {
        float m = fmaxf(fmaxf(red[tid * 4], red[tid * 4 + 1]),
                        fmaxf(red[tid * 4 + 2], red[tid * 4 + 3]));
        mrow[tid] = m;
    }
    __syncthreads();
    if (tid < U * 4) {
        float m = mrow[su];
        int um = su & 15;
        float ls = 0.f;
        for (int t = 0; t < 32; t++) {
            int i = sq + 4 * t;
            int addr = su * SEG + 4 * ((i >> 2) ^ um) + (i & 3);
            float e = 0.f;
            if (i < nkc) e = __expf(Sc[addr] - m);
            Sc[addr] = e;
            ls += e;
        }
        red[su * 4 + sq] = ls;
    }
    __syncthreads();   // (C)
    if (tid < U) {
        float ls = (red[tid * 4] + red[tid * 4 + 1]) + (red[tid * 4 + 2] + red[tid * 4 + 3]);
        size_t mli = 2 * ((size_t)(bh * U + tid) * NSEG + seg);
        ml[mli]     = mrow[tid];
        ml[mli + 1] = ls;
    }

    // ---- PV GEMM: thread tile 5u x 2d ----
    int vg = jg;
    float a2[5][2];
#pragma unroll
    for (int uu = 0; uu < 5; uu++) { a2[uu][0] = 0.f; a2[uu][1] = 0.f; }

    for (int j4 = 0; j4 < 32; j4++) {
        float4 pf[5];
#pragma unroll
        for (int uu = 0; uu < 5; uu++) {
            int u = ug * 5 + uu;
            pf[uu] = *(const float4*)&Sc[u * SEG + 4 * (j4 ^ (u & 15))];
        }
#pragma unroll
        for (int jj = 0; jj < 4; jj++) {
            int j = j4 * 4 + jj;
            int fo = 4 * ((vg >> 1) ^ (j & 15)) + ((2 * vg) & 3);
            float2 vv = *(const float2*)&KV[j * D + fo];
#pragma unroll
            for (int uu = 0; uu < 5; uu++) {
                float p = ((const float*)&pf[uu])[jj];
                a2[uu][0] += p * vv.x;
                a2[uu][1] += p * vv.y;
            }
        }
    }
#pragma unroll
    for (int uu = 0; uu < 5; uu++) {
        int u = ug * 5 + uu;
        float2 w2 = make_float2(a2[uu][0], a2[uu][1]);
        *(float2*)&pacc[((size_t)(bh * U + u) * NSEG + seg) * D + 2 * vg] = w2;
    }
}

// ---------------------------------------------------------------------------
// K5b: combine NSEG partials; 4 u-rows per 256-thread block (320 blocks).
// ---------------------------------------------------------------------------
__global__ void attn_combine(const int* __restrict__ Mtop,
                             const float* __restrict__ ml,
                             const float* __restrict__ pacc,
                             float* __restrict__ out) {
    int row = blockIdx.x * 4 + (threadIdx.x >> 6);  // bh*U + u
    int u  = row % U;
    int bh = row / U;
    int h  = bh % H;
    int b  = bh / H;
    int d  = threadIdx.x & 63;
    int qi = Mtop[bh * U + u];

    size_t r0 = (size_t)row * NSEG;
    float m = -INFINITY;
#pragma unroll
    for (int s = 0; s < NSEG; s++) m = fmaxf(m, ml[2 * (r0 + s)]);

    float lt = 0.f, acc = 0.f;
#pragma unroll
    for (int s = 0; s < NSEG; s++) {
        float ms = ml[2 * (r0 + s)];
        float w  = __expf(ms - m);
        lt  += ml[2 * (r0 + s) + 1] * w;
        acc += pacc[(r0 + s) * D + d] * w;
    }
    out[((size_t)(b * L + qi) * H + h) * D + d] = acc / lt;
}

// ---------------------------------------------------------------------------
extern "C" void kernel_launch(void* const* d_in, const int* in_sizes, int n_in,
                              void* d_out, int out_size, void* d_ws, size_t ws_size,
                              hipStream_t stream) {
    const float* q    = (const float*)d_in[0];
    const float* k    = (const float*)d_in[1];
    const float* v    = (const float*)d_in[2];
    const int*   samp = (const int*)d_in[3];
    float* out = (float*)d_out;

    // workspace layout
    float* M    = (float*)d_ws;                        // B*H*L
    int*   Mtop = (int*)(M + (size_t)B * H * L);       // B*H*U
    float* part = (float*)(Mtop + (size_t)B * H * U);  // B*H*C*D
    float* ml   = part + (size_t)B * H * C * D;        // B*H*U*NSEG*2
    float* pacc = ml + (size_t)B * H * U * NSEG * 2;   // B*H*U*NSEG*D

    fused_Mpart<<<256 + B * L, 256, 0, stream>>>(q, k, v, samp, M, part);
    fused_topk_cumsum<<<32 + 1024, 64, 0, stream>>>(M, v, part, Mtop, out);
    attn_batched<<<B * H * NSEG, 256, 0, stream>>>(q, k, v, Mtop, ml, pacc);
    attn_combine<<<B * H * U / 4, 256, 0, stream>>>(Mtop, ml, pacc, out);
}

// Round 9
// 158.513 us; speedup vs baseline: 1.9974x; 1.1631x over previous
//
#include <hip/hip_runtime.h>
#include <hip/hip_bf16.h>
#include <math.h>

// Problem constants (fixed by setup_inputs)
constexpr int B = 4;
constexpr int L = 2048;
constexpr int H = 8;
constexpr int D = 64;
constexpr int S = 40;   // sample_k
constexpr int U = 40;   // top-u queries
constexpr int C = 32;   // cumsum chunks
constexpr int CHUNK = L / C;   // 64
constexpr int NSEG = 16;       // key segments for attention
constexpr int SEG  = L / NSEG; // 128
constexpr int PAH  = 688;      // per-h LDS stride

// ---------------------------------------------------------------------------
// L1 fat kernel: blocks [0,256) = cumsum_part; blocks [256, 256+B*L) = compute_M.
// ---------------------------------------------------------------------------
__global__ void fused_Mpart(const float* __restrict__ q,
                            const float* __restrict__ k,
                            const float* __restrict__ v,
                            const int*   __restrict__ samp,
                            float* __restrict__ M,
                            float* __restrict__ part) {
    __shared__ float pa[H * PAH];
    int tid = threadIdx.x;

    if (blockIdx.x < 256) {
        // ---- cumsum_part ----
        int idx = blockIdx.x * 256 + tid;   // [0, B*C*H*D) = 65536
        int b   = idx >> 14;
        int rem = idx & 16383;
        int c   = rem >> 9;
        int hd  = rem & 511;
        const float* base = v + ((size_t)(b * L + c * CHUNK) * H * D) + hd;
        float s = 0.f;
        for (int i = 0; i < CHUNK; i++) s += base[(size_t)i * (H * D)];
        int h = hd >> 6, d = hd & 63;
        part[((size_t)(b * H + h) * C + c) * D + d] = s;
        return;
    }

    // ---- compute_M ----
    int blk = blockIdx.x - 256;        // [0, B*L)
    int xcd = blk & 7;
    int b   = xcd >> 1;
    int l   = ((blk >> 3) << 1) | (xcd & 1);
    int h      = tid >> 5;             // 0..7
    int lane32 = tid & 31;
    int g  = lane32 >> 4;              // sample sub-slot (0..1)
    int d4 = lane32 & 15;              // float4 index within row

    const float4 qv = *(const float4*)(q + ((size_t)(b * L + l) * H + h) * D + d4 * 4);
    const int* srow = samp + l * S;
    float* pah = pa + h * PAH;

#pragma unroll 10
    for (int sb = 0; sb < S; sb += 2) {
        int i0 = srow[sb];
        int i1 = srow[sb + 1];
        int idx = g ? i1 : i0;
        int s = sb + g;
        float4 kv = *(const float4*)(k + ((size_t)(b * L + idx) * H + h) * D + d4 * 4);
        pah[s * 17 + d4] = qv.x * kv.x + qv.y * kv.y + qv.z * kv.z + qv.w * kv.w;
    }
    __syncthreads();

    int s1 = lane32;
    float t0 = 0.f, t1 = 0.f, t2 = 0.f, t3 = 0.f;
#pragma unroll
    for (int i = 0; i < 16; i += 4) {
        t0 += pah[s1 * 17 + i];
        t1 += pah[s1 * 17 + i + 1];
        t2 += pah[s1 * 17 + i + 2];
        t3 += pah[s1 * 17 + i + 3];
    }
    float dot1 = (t0 + t1) + (t2 + t3);
    float mv = dot1, sv = dot1;
    if (lane32 < S - 32) {
        int s2 = 32 + lane32;
        float u0 = 0.f, u1 = 0.f, u2 = 0.f, u3 = 0.f;
#pragma unroll
        for (int i = 0; i < 16; i += 4) {
            u0 += pah[s2 * 17 + i];
            u1 += pah[s2 * 17 + i + 1];
            u2 += pah[s2 * 17 + i + 2];
            u3 += pah[s2 * 17 + i + 3];
        }
        float dot2 = (u0 + u1) + (u2 + u3);
        mv = fmaxf(mv, dot2);
        sv += dot2;
    }
#pragma unroll
    for (int off = 1; off <= 16; off <<= 1) {
        mv = fmaxf(mv, __shfl_xor(mv, off));
        sv += __shfl_xor(sv, off);
    }
    if (lane32 == 0) M[(size_t)(b * H + h) * L + l] = mv - sv * (1.0f / (float)L);
}

// ---------------------------------------------------------------------------
// L2 fat kernel, 64 threads/block.
// blocks [0,32): topk via 4-pass radix select (8 bits/pass on sortable keys).
//   One wave per (b,h). After the passes, vstar = exact 40th-largest value and
//   Rstar = #ties to take; emission via two wave prefix-sums. Tie-break =
//   lowest index is automatic: lane/slot order IS index order.
// blocks [32, 32+1024): cumsum_write.
// ---------------------------------------------------------------------------
__global__ void fused_topk_cumsum(const float* __restrict__ M,
                                  const float* __restrict__ v,
                                  const float* __restrict__ part,
                                  int* __restrict__ Mtop,
                                  float* __restrict__ out) {
    int tid = threadIdx.x;   // 0..63

    if (blockIdx.x >= 32) {
        // ---- cumsum_write ----
        int idx = (blockIdx.x - 32) * 64 + tid;   // [0, 65536)
        int b   = idx >> 14;
        int rem = idx & 16383;
        int c   = rem >> 9;                        // block-uniform
        int hd  = rem & 511;
        int h = hd >> 6, d = hd & 63;

        float run = 0.f;
        for (int cc = 0; cc < c; cc++)
            run += part[((size_t)(b * H + h) * C + cc) * D + d];

        const float* base  = v   + ((size_t)(b * L + c * CHUNK) * H * D) + hd;
        float*       obase = out + ((size_t)(b * L + c * CHUNK) * H * D) + hd;
        for (int i = 0; i < CHUNK; i++) {
            run += base[(size_t)i * (H * D)];
            obase[(size_t)i * (H * D)] = run;
        }
        return;
    }

    // ---- topk: 4-pass radix select ----
    __shared__ unsigned hist[16 * 256];   // 16-way privatized 256-bin histogram
    __shared__ unsigned selS[2];          // {selected bin, new rank}

    int bh   = blockIdx.x;
    int lane = tid;
    int base = lane * 32;
    const float* row = M + (size_t)bh * L;

    unsigned vals[32];                    // sortable-u32: order == float order
#pragma unroll
    for (int r4 = 0; r4 < 8; r4++) {
        float4 f = *(const float4*)(row + base + r4 * 4);
        const float ff[4] = {f.x, f.y, f.z, f.w};
#pragma unroll
        for (int j = 0; j < 4; j++) {
            unsigned i = __float_as_uint(ff[j]);
            vals[r4 * 4 + j] = (i & 0x80000000u) ? ~i : (i | 0x80000000u);
        }
    }

    unsigned prefix = 0;
    unsigned R = U;                       // rank to find among matching elems
#pragma unroll
    for (int p = 0; p < 4; p++) {
        int sh = 24 - 8 * p;
        // zero histogram (vectorized)
        {
            uint4* h4 = (uint4*)hist;
#pragma unroll
            for (int i = 0; i < 16; i++) {
                h4[lane + i * 64] = make_uint4(0u, 0u, 0u, 0u);
            }
        }
        __syncthreads();
        unsigned pbase = (lane & 15) * 256;
#pragma unroll
        for (int r = 0; r < 32; r++) {
            unsigned vv = vals[r];
            bool match = (p == 0) || ((vv >> (sh + 8)) == prefix);
            if (match) atomicAdd(&hist[pbase + ((vv >> sh) & 255u)], 1u);
        }
        __syncthreads();
        // reduce 16 privs, 4 bins per lane
        int b0 = lane * 4;
        unsigned c0 = 0, c1 = 0, c2 = 0, c3 = 0;
#pragma unroll
        for (int pp = 0; pp < 16; pp++) {
            const unsigned* hp = &hist[pp * 256 + b0];
            c0 += hp[0]; c1 += hp[1]; c2 += hp[2]; c3 += hp[3];
        }
        unsigned t = c0 + c1 + c2 + c3;
        // inclusive suffix-scan of lane totals
        unsigned s = t;
#pragma unroll
        for (int off = 1; off < 64; off <<= 1) {
            unsigned n = __shfl_down(s, off);
            if (lane + off < 64) s += n;
        }
        unsigned Sx = s - t;              // elements in lanes > lane
        unsigned suf3 = Sx;
        unsigned suf2 = Sx + c3;
        unsigned suf1 = Sx + c3 + c2;
        unsigned suf0 = Sx + c3 + c2 + c1;
        if (suf0 < R && R <= suf0 + c0) { selS[0] = b0;     selS[1] = R - suf0; }
        if (suf1 < R && R <= suf1 + c1) { selS[0] = b0 + 1; selS[1] = R - suf1; }
        if (suf2 < R && R <= suf2 + c2) { selS[0] = b0 + 2; selS[1] = R - suf2; }
        if (suf3 < R && R <= suf3 + c3) { selS[0] = b0 + 3; selS[1] = R - suf3; }
        __syncthreads();
        prefix = (prefix << 8) | selS[0];
        R = selS[1];
        __syncthreads();
    }
    unsigned vstar = prefix;              // exact 40th-largest value
    unsigned Rstar = R;                   // how many == vstar to take
    unsigned n1 = U - Rstar;              // # strictly greater

    // emission: counts + wave exclusive prefix (lane order == index order)
    unsigned cgt = 0, ceq = 0;
#pragma unroll
    for (int r = 0; r < 32; r++) {
        cgt += (vals[r] > vstar) ? 1u : 0u;
        ceq += (vals[r] == vstar) ? 1u : 0u;
    }
    unsigned ig = cgt, iq = ceq;
#pragma unroll
    for (int off = 1; off < 64; off <<= 1) {
        unsigned ng = __shfl_up(ig, off);
        unsigned nq = __shfl_up(iq, off);
        if (lane >= off) { ig += ng; iq += nq; }
    }
    unsigned goff = ig - cgt;             // exclusive prefix of > counts
    unsigned toff = iq - ceq;             // exclusive prefix of == counts
    int p1 = (int)goff;
    int pt = (int)(n1 + toff);
    unsigned kk = 0;
#pragma unroll
    for (int r = 0; r < 32; r++) {
        unsigned vv = vals[r];
        if (vv > vstar) {
            Mtop[bh * U + p1] = base + r;
            p1++;
        } else if (vv == vstar) {
            if (toff + kk < Rstar) { Mtop[bh * U + pt] = base + r; pt++; }
            kk++;
        }
    }
}

// ---------------------------------------------------------------------------
// K5a: batched-query segment attention (known-good R6 version).
// ---------------------------------------------------------------------------
__global__ __launch_bounds__(256, 2)
void attn_batched(const float* __restrict__ q,
                  const float* __restrict__ k,
                  const float* __restrict__ v,
                  const int*   __restrict__ Mtop,
                  float* __restrict__ ml,
                  float* __restrict__ pacc) {
    int blk = blockIdx.x;              // [0, B*H*NSEG) = 512
    int xcd = blk & 7;
    int b   = xcd >> 1;
    int r   = ((blk >> 3) << 1) | (xcd & 1);   // [0, H*NSEG)
    int h   = r >> 4;
    int seg = r & 15;
    int bh  = b * H + h;
    int j0  = seg * SEG;
    int tid = threadIdx.x;

    __shared__ float Qs[U * D];        // 10.2 KB
    __shared__ float KV[SEG * D];      // 32.8 KB (K tile, then reused for V)
    __shared__ float Sc[U * SEG];      // 20.5 KB (slot-swizzled by u&15)
    __shared__ float red[U * 4];
    __shared__ float mrow[U];
    __shared__ int   qis[U];

    if (tid < U) qis[tid] = Mtop[bh * U + tid];
    __syncthreads();

    for (int i = tid; i < U * 16; i += 256) {
        int u = i >> 4, d4 = i & 15;
        *(float4*)&Qs[u * D + d4 * 4] =
            *(const float4*)(q + ((size_t)(b * L + qis[u]) * H + h) * D + d4 * 4);
    }
    for (int i = tid; i < SEG * 16; i += 256) {
        int rr = i >> 4, d4 = i & 15;
        float4 kv = *(const float4*)(k + ((size_t)(b * L + j0 + rr) * H + h) * D + d4 * 4);
        *(float4*)&KV[rr * D + (d4 ^ (rr & 15)) * 4] = kv;
    }
    __syncthreads();

    // ---- score GEMM: thread tile 5u x 4j ----
    int ug = tid >> 5;        // 0..7
    int jg = tid & 31;        // 0..31
    int jlow = jg & 15;
    float acc[5][4];
#pragma unroll
    for (int uu = 0; uu < 5; uu++)
#pragma unroll
        for (int jj = 0; jj < 4; jj++) acc[uu][jj] = 0.f;

#pragma unroll
    for (int kk4 = 0; kk4 < 16; kk4++) {
        float4 kf[4];
        int slot = kk4 ^ jlow;
#pragma unroll
        for (int jj = 0; jj < 4; jj++)
            kf[jj] = *(const float4*)&KV[(jg + 32 * jj) * D + slot * 4];
#pragma unroll
        for (int uu = 0; uu < 5; uu++) {
            float4 qf = *(const float4*)&Qs[(ug * 5 + uu) * D + kk4 * 4];
#pragma unroll
            for (int jj = 0; jj < 4; jj++) {
                acc[uu][jj] += qf.x * kf[jj].x + qf.y * kf[jj].y
                             + qf.z * kf[jj].z + qf.w * kf[jj].w;
            }
        }
    }
#pragma unroll
    for (int uu = 0; uu < 5; uu++) {
        int u = ug * 5 + uu;
        int um = u & 15;
#pragma unroll
        for (int jj = 0; jj < 4; jj++) {
            int j = jg + 32 * jj;
            Sc[u * SEG + 4 * ((j >> 2) ^ um) + (j & 3)] = acc[uu][jj] * 0.125f;
        }
    }
    __syncthreads();   // (A): Sc visible; all K reads done

    // stage V tile into KV
    for (int i = tid; i < SEG * 16; i += 256) {
        int rr = i >> 4, d4 = i & 15;
        float4 vv = *(const float4*)(v + ((size_t)(b * L + j0 + rr) * H + h) * D + d4 * 4);
        *(float4*)&KV[rr * D + (d4 ^ (rr & 15)) * 4] = vv;
    }

    // ---- masked softmax partials ----
    int su = tid >> 2, sq = tid & 3;
    int nkc = 0;
    if (tid < U * 4) {
        int nk = qis[su] + 1 - j0;
        nkc = nk < 0 ? 0 : (nk > SEG ? SEG : nk);
        int um = su & 15;
        float mvx = -INFINITY;
        for (int t = 0; t < 32; t++) {
            int i = sq + 4 * t;
            if (i < nkc) mvx = fmaxf(mvx, Sc[su * SEG + 4 * ((i >> 2) ^ um) + (i & 3)]);
        }
        red[su * 4 + sq] = mvx;
    }
    __syncthreads();   // (B): also covers V staging
    if (tid < U) {
        float m = fmaxf(fmaxf(red[tid * 4], red[tid * 4 + 1]),
                        fmaxf(red[tid * 4 + 2], red[tid * 4 + 3]));
        mrow[tid] = m;
    }
    __syncthreads();
    if (tid < U * 4) {
        float m = mrow[su];
        int um = su & 15;
        float ls = 0.f;
        for (int t = 0; t < 32; t++) {
            int i = sq + 4 * t;
            int addr = su * SEG + 4 * ((i >> 2) ^ um) + (i & 3);
            float e = 0.f;
            if (i < nkc) e = __expf(Sc[addr] - m);
            Sc[addr] = e;
            ls += e;
        }
        red[su * 4 + sq] = ls;
    }
    __syncthreads();   // (C)
    if (tid < U) {
        float ls = (red[tid * 4] + red[tid * 4 + 1]) + (red[tid * 4 + 2] + red[tid * 4 + 3]);
        size_t mli = 2 * ((size_t)(bh * U + tid) * NSEG + seg);
        ml[mli]     = mrow[tid];
        ml[mli + 1] = ls;
    }

    // ---- PV GEMM: thread tile 5u x 2d ----
    int vg = jg;
    float a2[5][2];
#pragma unroll
    for (int uu = 0; uu < 5; uu++) { a2[uu][0] = 0.f; a2[uu][1] = 0.f; }

    for (int j4 = 0; j4 < 32; j4++) {
        float4 pf[5];
#pragma unroll
        for (int uu = 0; uu < 5; uu++) {
            int u = ug * 5 + uu;
            pf[uu] = *(const float4*)&Sc[u * SEG + 4 * (j4 ^ (u & 15))];
        }
#pragma unroll
        for (int jj = 0; jj < 4; jj++) {
            int j = j4 * 4 + jj;
            int fo = 4 * ((vg >> 1) ^ (j & 15)) + ((2 * vg) & 3);
            float2 vv = *(const float2*)&KV[j * D + fo];
#pragma unroll
            for (int uu = 0; uu < 5; uu++) {
                float p = ((const float*)&pf[uu])[jj];
                a2[uu][0] += p * vv.x;
                a2[uu][1] += p * vv.y;
            }
        }
    }
#pragma unroll
    for (int uu = 0; uu < 5; uu++) {
        int u = ug * 5 + uu;
        float2 w2 = make_float2(a2[uu][0], a2[uu][1]);
        *(float2*)&pacc[((size_t)(bh * U + u) * NSEG + seg) * D + 2 * vg] = w2;
    }
}

// ---------------------------------------------------------------------------
// K5b: combine NSEG partials; 4 u-rows per 256-thread block (320 blocks).
// ---------------------------------------------------------------------------
__global__ void attn_combine(const int* __restrict__ Mtop,
                             const float* __restrict__ ml,
                             const float* __restrict__ pacc,
                             float* __restrict__ out) {
    int row = blockIdx.x * 4 + (threadIdx.x >> 6);  // bh*U + u
    int u  = row % U;
    int bh = row / U;
    int h  = bh % H;
    int b  = bh / H;
    int d  = threadIdx.x & 63;
    int qi = Mtop[bh * U + u];

    size_t r0 = (size_t)row * NSEG;
    float m = -INFINITY;
#pragma unroll
    for (int s = 0; s < NSEG; s++) m = fmaxf(m, ml[2 * (r0 + s)]);

    float lt = 0.f, acc = 0.f;
#pragma unroll
    for (int s = 0; s < NSEG; s++) {
        float ms = ml[2 * (r0 + s)];
        float w  = __expf(ms - m);
        lt  += ml[2 * (r0 + s) + 1] * w;
        acc += pacc[(r0 + s) * D + d] * w;
    }
    out[((size_t)(b * L + qi) * H + h) * D + d] = acc / lt;
}

// ---------------------------------------------------------------------------
extern "C" void kernel_launch(void* const* d_in, const int* in_sizes, int n_in,
                              void* d_out, int out_size, void* d_ws, size_t ws_size,
                              hipStream_t stream) {
    const float* q    = (const float*)d_in[0];
    const float* k    = (const float*)d_in[1];
    const float* v    = (const float*)d_in[2];
    const int*   samp = (const int*)d_in[3];
    float* out = (float*)d_out;

    // workspace layout
    float* M    = (float*)d_ws;                        // B*H*L
    int*   Mtop = (int*)(M + (size_t)B * H * L);       // B*H*U
    float* part = (float*)(Mtop + (size_t)B * H * U);  // B*H*C*D
    float* ml   = part + (size_t)B * H * C * D;        // B*H*U*NSEG*2
    float* pacc = ml + (size_t)B * H * U * NSEG * 2;   // B*H*U*NSEG*D

    fused_Mpart<<<256 + B * L, 256, 0, stream>>>(q, k, v, samp, M, part);
    fused_topk_cumsum<<<32 + 1024, 64, 0, stream>>>(M, v, part, Mtop, out);
    attn_batched<<<B * H * NSEG, 256, 0, stream>>>(q, k, v, Mtop, ml, pacc);
    attn_combine<<<B * H * U / 4, 256, 0, stream>>>(Mtop, ml, pacc, out);
}